// Round 1
// baseline (142.073 us; speedup 1.0000x reference)
//
#include <hip/hip_runtime.h>
#include <hip/hip_fp16.h>

#define T_LEN 16384
#define B_SZ  256
#define S_CH  256                // time chunks per direction
#define CL    (T_LEN / S_CH)     // 64 stored steps per chunk
#define HALO  32                 // burn-in steps (contractive recurrence)
#define SC    16                 // superchunk steps (SC=32 overflows vmcnt)

__device__ __forceinline__ float ex2(float x)  { return __builtin_amdgcn_exp2f(x); }
__device__ __forceinline__ float rcpf(float x) { return __builtin_amdgcn_rcpf(x); }

__device__ __forceinline__ float ld_cvt(const float* p)  { return *p; }
__device__ __forceinline__ float ld_cvt(const __half* p) { return __half2float(*p); }
__device__ __forceinline__ void  st_cvt(float* p, float v)  { *p = v; }
__device__ __forceinline__ void  st_cvt(__half* p, float v) { *p = __float2half_rn(v); }

// One GRU step, H=1. UR,UZ pre-scaled by -log2e; UN2,DN2 by +2log2e.
__device__ __forceinline__ float gru_step(float h, float preR, float preZ, float preN,
                                          float UR, float UZ, float UN2, float DN2)
{
    float er  = ex2(fmaf(h, UR, preR));
    float ez  = ex2(fmaf(h, UZ, preZ));
    float r   = rcpf(1.0f + er);
    float z   = rcpf(1.0f + ez);
    float hn2 = fmaf(h, UN2, DN2);                    // off critical path
    float en  = ex2(fmaf(r, hn2, preN));
    float n   = fmaf(-2.0f, rcpf(1.0f + en), 1.0f);   // tanh via exp2
    float omz = 1.0f - z;
    float zh  = z * h;
    return fmaf(n, omz, zh);
}

// ---- Layer 0 scan: unchanged from previous version ----
template<bool REV>
__device__ void scan0(const float* __restrict__ x,
                      const float* __restrict__ wih, const float* __restrict__ whh,
                      const float* __restrict__ bih, const float* __restrict__ bhh,
                      __half* __restrict__ out, int b, int s)
{
    const int d = REV ? 1 : 0;
    const float L2E = 1.4426950408889634f;
    const float WR  = -L2E * wih[d*3+0];
    const float WZ  = -L2E * wih[d*3+1];
    const float WN  =  2.0f*L2E * wih[d*3+2];
    const float UR  = -L2E * whh[d*3+0];
    const float UZ  = -L2E * whh[d*3+1];
    const float UN2 =  2.0f*L2E * whh[d*3+2];
    const float CR  = -L2E * (bih[d*3+0] + bhh[d*3+0]);
    const float CZ  = -L2E * (bih[d*3+1] + bhh[d*3+1]);
    const float CN  =  2.0f*L2E * bih[d*3+2];
    const float DN2 =  2.0f*L2E * bhh[d*3+2];

    const int warm   = min(HALO, REV ? (T_LEN - (s + 1) * CL) : (s * CL));
    const int nsteps = warm + CL;           // {64,96}: nsup in {4,6}, always even
    const int t0     = REV ? ((s + 1) * CL - 1 + warm) : (s * CL - warm);

    const float* row = x + (size_t)b * T_LEN;
    __half* po = out + (REV ? B_SZ : 0) + b;   // [t][2][b]

    float xA[SC], xB[SC];
    float h = 0.0f;

    auto LD = [&](float* F, int base) {
        const float4* p = (const float4*)(row + (REV ? (t0 - base - 15) : (t0 + base)));
        float4 v0 = p[0], v1 = p[1], v2 = p[2], v3 = p[3];
        float lin[16] = { v0.x,v0.y,v0.z,v0.w, v1.x,v1.y,v1.z,v1.w,
                          v2.x,v2.y,v2.z,v2.w, v3.x,v3.y,v3.z,v3.w };
        #pragma unroll
        for (int k = 0; k < 16; ++k) F[k] = REV ? lin[15 - k] : lin[k];
        __builtin_amdgcn_sched_barrier(0);
    };

    auto CS = [&](float* F, int base) {
        float ov[SC];
        #pragma unroll
        for (int k = 0; k < SC; ++k) {
            float xv = F[k];
            h = gru_step(h, fmaf(xv, WR, CR), fmaf(xv, WZ, CZ), fmaf(xv, WN, CN),
                         UR, UZ, UN2, DN2);
            ov[k] = h;
        }
        if (base >= warm) {
            #pragma unroll
            for (int k = 0; k < SC; ++k) {
                int t = REV ? (t0 - (base + k)) : (t0 + (base + k));
                st_cvt(po + t * (2 * B_SZ), ov[k]);
            }
        }
    };

    LD(xA, 0);
    const int nsup = nsteps / SC;
    for (int i = 0; i < nsup; i += 2) {
        LD(xB, min((i + 1) * SC, nsteps - SC));
        CS(xA, i * SC);
        LD(xA, min((i + 2) * SC, nsteps - SC));
        CS(xB, (i + 1) * SC);
    }
}

__device__ __forceinline__ void decode_blk(int blk, int tid, int& b, int& s, int& dir)
{
    int xcd = blk & 7;
    int j   = blk >> 3;            // 0..255
    int sl  = j & 31;
    int bg  = (j >> 5) & 3;
    dir     = j >> 7;
    s       = xcd * 32 + sl;
    b       = bg * 64 + tid;
}

__global__ void __launch_bounds__(64) k_scan0g(const float* __restrict__ x,
                                               const float* __restrict__ wih,
                                               const float* __restrict__ whh,
                                               const float* __restrict__ bih,
                                               const float* __restrict__ bhh,
                                               __half* __restrict__ out)
{
    int b, s, dir;
    decode_blk(blockIdx.x, threadIdx.x, b, s, dir);
    if (dir == 0) scan0<false>(x, wih, whh, bih, bhh, out, b, s);
    else          scan0<true >(x, wih, whh, bih, bhh, out, b, s);
}

// =======================================================================
// Fused L1 + L2 + projection kernel.
// 1024 blocks x 128 threads. wave0 = fwd dir, wave1 = bwd dir.
// L1 computes window [a1-warm1, e1) reading l0out (global, half), stores
// [a1, e1) (<=128 steps) to LDS half. L2 reads both LDS streams, keeps its
// 64 stored h2 in registers (compile-time indexed), then proj+transpose
// reuses the freed LDS for a coalesced float4 store of y.
// =======================================================================
__global__ void __launch_bounds__(128) k12p(const __half* __restrict__ in,
        const float* __restrict__ w_ih12, const float* __restrict__ w_hh12,
        const float* __restrict__ b_ih12, const float* __restrict__ b_hh12,
        const float* __restrict__ wo, const float* __restrict__ bo,
        float* __restrict__ y)
{
    __shared__ __align__(16) char smem[33024];
    __half (*lds1)[2][64] = reinterpret_cast<__half(*)[2][64]>(smem);      // 32768 B
    float  (*tG)[64]      = reinterpret_cast<float(*)[64]>(smem);          // aliases lds1
    float  (*tY)[65]      = reinterpret_cast<float(*)[65]>(smem + 16384);  // 16640 B

    // XCD swizzle: xcd owns chunks [xcd*32, xcd*32+32) -> halo re-reads stay in L2
    const int blk  = blockIdx.x;
    const int xcd  = blk & 7;
    const int jj_  = blk >> 3;          // 0..127
    const int sl   = jj_ & 31;
    const int bg   = jj_ >> 5;          // 0..3
    const int s    = xcd * 32 + sl;
    const int lane = threadIdx.x & 63;
    const int w    = threadIdx.x >> 6;  // 0 fwd, 1 bwd
    const int b    = bg * 64 + lane;
    const int sg   = w ? -1 : 1;

    const int t0     = s * CL;
    const int warmF2 = min(HALO, t0);
    const int warmB2 = min(HALO, T_LEN - (t0 + CL));
    const int a1     = t0 - warmF2;            // L2 window = [a1, e1)
    const int e1     = t0 + CL + warmB2;
    const int L      = e1 - a1;                // 96..128

    const float L2E = 1.4426950408889634f;

    // ---------------- L1 scan (dir = w), output -> LDS ----------------
    {
        const int d = w;
        const float WR0 = -L2E * w_ih12[(d*3+0)*2+0], WR1 = -L2E * w_ih12[(d*3+0)*2+1];
        const float WZ0 = -L2E * w_ih12[(d*3+1)*2+0], WZ1 = -L2E * w_ih12[(d*3+1)*2+1];
        const float WN0 =  2.0f*L2E * w_ih12[(d*3+2)*2+0], WN1 = 2.0f*L2E * w_ih12[(d*3+2)*2+1];
        const float UR  = -L2E * w_hh12[d*3+0];
        const float UZ  = -L2E * w_hh12[d*3+1];
        const float UN2 =  2.0f*L2E * w_hh12[d*3+2];
        const float CR  = -L2E * (b_ih12[d*3+0] + b_hh12[d*3+0]);
        const float CZ  = -L2E * (b_ih12[d*3+1] + b_hh12[d*3+1]);
        const float CN  =  2.0f*L2E * b_ih12[d*3+2];
        const float DN2 =  2.0f*L2E * b_hh12[d*3+2];

        const int warm1   = w ? min(HALO, T_LEN - e1) : min(HALO, a1);
        const int nsteps1 = warm1 + L;          // {96,128,160}: nsup even
        const int tstart1 = w ? (e1 - 1 + warm1) : (a1 - warm1);

        const __half* pf = in + b;
        const __half* pg = in + B_SZ + b;

        float fA[SC], gA[SC], fB[SC], gB[SC];
        float h = 0.0f;

#define LD1(F, G, base_) { int base = (base_); \
    _Pragma("unroll") for (int k = 0; k < SC; ++k) { \
      int t = tstart1 + sg * (base + k); \
      F[k] = ld_cvt(pf + t * (2 * B_SZ)); G[k] = ld_cvt(pg + t * (2 * B_SZ)); } \
    __builtin_amdgcn_sched_barrier(0); }

#define CS1(F, G, base_) { int base = (base_); float ov[SC]; \
    _Pragma("unroll") for (int k = 0; k < SC; ++k) { \
      float a = F[k], c = G[k]; \
      float pr = fmaf(a, WR0, fmaf(c, WR1, CR)); \
      float pz = fmaf(a, WZ0, fmaf(c, WZ1, CZ)); \
      float pn = fmaf(a, WN0, fmaf(c, WN1, CN)); \
      h = gru_step(h, pr, pz, pn, UR, UZ, UN2, DN2); ov[k] = h; } \
    if (base >= warm1) { \
      _Pragma("unroll") for (int k = 0; k < SC; ++k) { \
        int t = tstart1 + sg * (base + k); \
        lds1[t - a1][d][lane] = __float2half_rn(ov[k]); } } }

        LD1(fA, gA, 0);
        const int nsup = nsteps1 / SC;
        for (int i = 0; i < nsup; i += 2) {
            LD1(fB, gB, min((i + 1) * SC, nsteps1 - SC));
            CS1(fA, gA, i * SC);
            LD1(fA, gA, min((i + 2) * SC, nsteps1 - SC));
            CS1(fB, gB, (i + 1) * SC);
        }
#undef LD1
#undef CS1
    }
    __syncthreads();

    // ---------------- L2 scan (dir = w), LDS -> registers ----------------
    float f[CL];                                 // stored h2, compile-time indexed
    {
        const int d = w;
        const float* wih2 = w_ih12 + 12;
        const float* whh2 = w_hh12 + 6;
        const float* bih2 = b_ih12 + 6;
        const float* bhh2 = b_hh12 + 6;
        const float WR0 = -L2E * wih2[(d*3+0)*2+0], WR1 = -L2E * wih2[(d*3+0)*2+1];
        const float WZ0 = -L2E * wih2[(d*3+1)*2+0], WZ1 = -L2E * wih2[(d*3+1)*2+1];
        const float WN0 =  2.0f*L2E * wih2[(d*3+2)*2+0], WN1 = 2.0f*L2E * wih2[(d*3+2)*2+1];
        const float UR  = -L2E * whh2[d*3+0];
        const float UZ  = -L2E * whh2[d*3+1];
        const float UN2 =  2.0f*L2E * whh2[d*3+2];
        const float CR  = -L2E * (bih2[d*3+0] + bhh2[d*3+0]);
        const float CZ  = -L2E * (bih2[d*3+1] + bhh2[d*3+1]);
        const float CN  =  2.0f*L2E * bih2[d*3+2];
        const float DN2 =  2.0f*L2E * bhh2[d*3+2];

        const int warm2 = w ? warmB2 : warmF2;   // {0,32}, wave-uniform
        const int idx0  = w ? (L - 1) : 0;
        float h = 0.0f;

        // burn-in (rolled; 0 or 2 superchunks; no register-array stores)
        for (int jj = 0; jj < warm2; jj += SC) {
            float av[SC], cv[SC];
            #pragma unroll
            for (int k = 0; k < SC; ++k) {
                int idx = idx0 + sg * (jj + k);
                av[k] = __half2float(lds1[idx][0][lane]);
                cv[k] = __half2float(lds1[idx][1][lane]);
            }
            #pragma unroll
            for (int k = 0; k < SC; ++k) {
                float pr = fmaf(av[k], WR0, fmaf(cv[k], WR1, CR));
                float pz = fmaf(av[k], WZ0, fmaf(cv[k], WZ1, CZ));
                float pn = fmaf(av[k], WN0, fmaf(cv[k], WN1, CN));
                h = gru_step(h, pr, pz, pn, UR, UZ, UN2, DN2);
            }
        }
        // stored 64 steps (fully unrolled -> f[] stays in registers)
        #pragma unroll
        for (int q = 0; q < CL / SC; ++q) {
            float av[SC], cv[SC];
            #pragma unroll
            for (int k = 0; k < SC; ++k) {
                int idx = idx0 + sg * (warm2 + q * SC + k);
                av[k] = __half2float(lds1[idx][0][lane]);
                cv[k] = __half2float(lds1[idx][1][lane]);
            }
            #pragma unroll
            for (int k = 0; k < SC; ++k) {
                float pr = fmaf(av[k], WR0, fmaf(cv[k], WR1, CR));
                float pz = fmaf(av[k], WZ0, fmaf(cv[k], WZ1, CZ));
                float pn = fmaf(av[k], WN0, fmaf(cv[k], WN1, CN));
                h = gru_step(h, pr, pz, pn, UR, UZ, UN2, DN2);
                f[q * SC + k] = h;
            }
        }
    }
    __syncthreads();            // all lds1 reads done; safe to alias

    // ---------------- projection + transpose ----------------
    if (w == 1) {               // bwd wave: publish g in time-ascending order
        #pragma unroll
        for (int m = 0; m < CL; ++m) tG[CL - 1 - m][lane] = f[m];
    }
    __syncthreads();
    if (w == 0) {               // fwd wave: combine into y-tile [b][t]
        const float wf = wo[0], wb = wo[1], bias = bo[0];
        #pragma unroll
        for (int m = 0; m < CL; ++m)
            tY[lane][m] = fmaf(wf, f[m], fmaf(wb, tG[m][lane], bias));
    }
    __syncthreads();
    // coalesced float4 store: 128 threads x 8 rows
    {
        const int b0 = bg * 64;
        const int c4 = threadIdx.x & 15;
        const int r  = (threadIdx.x >> 4) & 7;
        #pragma unroll
        for (int i = 0; i < 8; ++i) {
            int brow = r + 8 * i;
            float4 v = make_float4(tY[brow][c4*4+0], tY[brow][c4*4+1],
                                   tY[brow][c4*4+2], tY[brow][c4*4+3]);
            ((float4*)y)[(size_t)(b0 + brow) * (T_LEN / 4) + (t0 >> 2) + c4] = v;
        }
    }
}

extern "C" void kernel_launch(void* const* d_in, const int* in_sizes, int n_in,
                              void* d_out, int out_size, void* d_ws, size_t ws_size,
                              hipStream_t stream)
{
    (void)in_sizes; (void)n_in; (void)out_size; (void)ws_size;
    const float* x      = (const float*)d_in[0];
    const float* w_ih0  = (const float*)d_in[1];
    const float* w_hh0  = (const float*)d_in[2];
    const float* b_ih0  = (const float*)d_in[3];
    const float* b_hh0  = (const float*)d_in[4];
    const float* w_ih12 = (const float*)d_in[5];
    const float* w_hh12 = (const float*)d_in[6];
    const float* b_ih12 = (const float*)d_in[7];
    const float* b_hh12 = (const float*)d_in[8];
    const float* w_out  = (const float*)d_in[9];
    const float* b_out  = (const float*)d_in[10];
    float* y = (float*)d_out;

    // ws: l0out half [t][2][b], 16.8 MB
    __half* l0out = (__half*)d_ws;

    k_scan0g<<<8 * S_CH, 64, 0, stream>>>(x, w_ih0, w_hh0, b_ih0, b_hh0, l0out);
    k12p   <<<4 * S_CH, 128, 0, stream>>>(l0out, w_ih12, w_hh12, b_ih12, b_hh12,
                                          w_out, b_out, y);
}